// Round 5
// baseline (252.281 us; speedup 1.0000x reference)
//
#include <hip/hip_runtime.h>
#include <hip/hip_bf16.h>

#define NROW 1600
#define NEG  3200
#define ROWS_FLAT 25600

using bf16x8 = __attribute__((ext_vector_type(8))) short;
using f32x4  = __attribute__((ext_vector_type(4))) float;

__device__ __forceinline__ float bf2f(unsigned v) { return __uint_as_float(v << 16); }
__device__ __forceinline__ ushort f2bf(float f) {
  __hip_bfloat16 h = __float2bfloat16(f);
  return *(ushort*)&h;
}
__device__ __forceinline__ float load1(const ushort* p, size_t idx, int f32) {
  return f32 ? ((const float*)p)[idx] : bf2f(p[idx]);
}
__device__ __forceinline__ void load8(const ushort* p, size_t idx, int f32, float* o) {
  if (f32) {
    const float* q = (const float*)p;
    float4 a = *(const float4*)(q + idx);
    float4 b = *(const float4*)(q + idx + 4);
    o[0]=a.x; o[1]=a.y; o[2]=a.z; o[3]=a.w;
    o[4]=b.x; o[5]=b.y; o[6]=b.z; o[7]=b.w;
  } else {
    uint4 u = *(const uint4*)(p + idx);
    o[0]=bf2f(u.x & 0xffffu); o[1]=bf2f(u.x >> 16);
    o[2]=bf2f(u.y & 0xffffu); o[3]=bf2f(u.y >> 16);
    o[4]=bf2f(u.z & 0xffffu); o[5]=bf2f(u.z >> 16);
    o[6]=bf2f(u.w & 0xffffu); o[7]=bf2f(u.w >> 16);
  }
}

// ---------------- K0: dtype detection ----------------
__global__ void k_detect(const ushort* __restrict__ fe0, const ushort* __restrict__ fe1,
                         const ushort* __restrict__ W, const ushort* __restrict__ bias,
                         int* __restrict__ flags) {
  int lane = threadIdx.x & 63;
  const ushort* ptrs[4] = {fe0, fe1, W, bias};
  for (int t = 0; t < 4; t++) {
    unsigned e = ((unsigned)ptrs[t][2*lane] >> 7) & 0xffu;
    bool ok = (e >= 100u && e <= 140u);
    unsigned long long b = __ballot(ok);
    if (lane == 0) flags[t] = (__popcll(b) >= 40) ? 0 : 1;  // 0=bf16, 1=fp32
  }
}

// ---------------- K0b: Wt[n][k] = bf16(W[k][n]) ----------------
__global__ __launch_bounds__(256) void k_prepw(const ushort* __restrict__ W,
    const int* __restrict__ flags, ushort* __restrict__ Wt) {
  int n = blockIdx.x, k = threadIdx.x;
  int fW = flags[2];
  Wt[n*256 + k] = f2bf(load1(W, (size_t)k*256 + n, fW));
}

// ---------------- K1: MFMA projection + L2 normalize ----------------
// Tile: 64 rows/block, wave = 16 rows x 256 cols. A-tile and C-epilogue share LDS.
__global__ __launch_bounds__(256) void k_proj(const ushort* __restrict__ fe0,
    const ushort* __restrict__ fe1, const ushort* __restrict__ Wt,
    const ushort* __restrict__ bias, const int* __restrict__ flags,
    ushort* __restrict__ Pb) {
  __shared__ union {
    ushort x[64*256];      // 32 KB swizzled A-tile
    ushort c[4][16*264];   // 33.8 KB epilogue (stride 264 spreads banks)
  } sh;
  const int tid = threadIdx.x;
  const int w = tid >> 6, lane = tid & 63, q = lane >> 4, m = lane & 15;
  const int grow0 = blockIdx.x * 64;
  const int src1 = (grow0 >= ROWS_FLAT);
  const ushort* src = src1 ? fe1 : fe0;
  const int fSrc = flags[src1 ? 1 : 0];
  const int fB = flags[3];
  const size_t rbase = (size_t)(src1 ? (grow0 - ROWS_FLAT) : grow0) * 256;
  // stage 64 rows x 256 -> bf16 LDS (XOR swizzle phys_k = k ^ ((r&7)<<3))
  #pragma unroll
  for (int i = 0; i < 8; i++) {
    int l = tid + i*256;
    int r = l >> 5, kc = l & 31;
    float o[8];
    load8(src, rbase + (size_t)r*256 + kc*8, fSrc, o);
    uint4 u;
    u.x = (unsigned)f2bf(o[0]) | ((unsigned)f2bf(o[1]) << 16);
    u.y = (unsigned)f2bf(o[2]) | ((unsigned)f2bf(o[3]) << 16);
    u.z = (unsigned)f2bf(o[4]) | ((unsigned)f2bf(o[5]) << 16);
    u.w = (unsigned)f2bf(o[6]) | ((unsigned)f2bf(o[7]) << 16);
    *(uint4*)&sh.x[r*256 + ((kc*8) ^ ((r&7)<<3))] = u;
  }
  __syncthreads();
  f32x4 acc[16];
  #pragma unroll
  for (int nt = 0; nt < 16; nt++) {
    float bb = load1(bias, nt*16 + m, fB);
    f32x4 v = {bb, bb, bb, bb};
    acc[nt] = v;
  }
  const int r0 = w*16 + m;
  for (int k0 = 0; k0 < 256; k0 += 32) {
    bf16x8 a = *(const bf16x8*)&sh.x[r0*256 + ((k0 + q*8) ^ ((r0&7)<<3))];
    #pragma unroll
    for (int nt = 0; nt < 16; nt++) {
      bf16x8 b = *(const bf16x8*)(Wt + (size_t)(nt*16 + m)*256 + k0 + q*8);
      acc[nt] = __builtin_amdgcn_mfma_f32_16x16x32_bf16(a, b, acc[nt], 0, 0, 0);
    }
  }
  __syncthreads();   // A-tile dead; safe to overlay epilogue region
  // normalize rows (row = 4q+reg, col = nt*16+m) and park bf16 C in LDS
  #pragma unroll
  for (int reg = 0; reg < 4; reg++) {
    float s = 0.f;
    #pragma unroll
    for (int nt = 0; nt < 16; nt++) { float v = acc[nt][reg]; s += v*v; }
    s += __shfl_xor(s, 1, 64); s += __shfl_xor(s, 2, 64);
    s += __shfl_xor(s, 4, 64); s += __shfl_xor(s, 8, 64);
    float inv = 1.0f / sqrtf(s);
    #pragma unroll
    for (int nt = 0; nt < 16; nt++)
      sh.c[w][(4*q + reg)*264 + nt*16 + m] = f2bf(acc[nt][reg] * inv);
  }
  // vectorized permuted store: lane -> (r = lane>>2, c4 = lane&3), 8 chunks of 16B
  {
    int r = lane >> 2, c4 = lane & 3;
    int grow = grow0 + w*16 + r;
    int srcid = grow / ROWS_FLAT;
    int rem   = grow % ROWS_FLAT;
    int b  = rem / 1600;
    int t  = (rem / 100) & 15;
    int qq = rem % 100;
    size_t orow = ((size_t)(srcid*1600 + b*100 + qq) * 16 + t) * 256;
    #pragma unroll
    for (int it = 0; it < 8; it++) {
      int c = c4 + it*4;
      uint4 v = *(uint4*)&sh.c[w][r*264 + c*8];
      *(uint4*)(Pb + orow + c*8) = v;
    }
  }
}

// ---------------- K2a: bridge prep (Ab bf16), numer, softplus, bucketing ----------------
__global__ __launch_bounds__(256) void k_bridge(const ushort* __restrict__ Pb,
    const int* __restrict__ bridge, ushort* __restrict__ Ab,
    float* __restrict__ prm, float* __restrict__ numer,
    int* __restrict__ cnt, int* __restrict__ lst, float* __restrict__ wsum) {
  int i = blockIdx.x, c = threadIdx.x;
  int bh = bridge[i*3+0], bp = bridge[i*3+1], bt = bridge[i*3+2];
  float bhf = (float)bh, bpf = (float)bp, btf = (float)bt;
  float alpha = (bpf - bhf) / (btf - bhf);
  float sigma = alpha * (btf - bpf);
  const ushort* base = Pb + (size_t)i * 16 * 256;
  float g0 = bf2f(base[bh*256 + c]), g1 = bf2f(base[bp*256 + c]), g2 = bf2f(base[bt*256 + c]);
  float head = bf2f(base[c]), tail = bf2f(base[15*256 + c]);
  float a = (1.0f - alpha) * g0 + alpha * g2;
  float x = g1 - a;
  Ab[(size_t)i*256 + c] = f2bf(a);
  float xx = x*x, aac = a*a, sc = head*tail;
  #pragma unroll
  for (int mk = 1; mk < 64; mk <<= 1) {
    xx  += __shfl_xor(xx, mk, 64);
    aac += __shfl_xor(aac, mk, 64);
    sc  += __shfl_xor(sc, mk, 64);
  }
  __shared__ float red[3][4];
  int wv = c >> 6;
  if ((c & 63) == 0) { red[0][wv]=xx; red[1][wv]=aac; red[2][wv]=sc; }
  __syncthreads();
  if (c == 0) {
    float XX = red[0][0]+red[0][1]+red[0][2]+red[0][3];
    float AA = red[1][0]+red[1][1]+red[1][2]+red[1][3];
    float SC = red[2][0]+red[2][1]+red[2][2]+red[2][3];
    float inv2s2 = 1.0f / (2.0f * sigma * sigma);
    prm[i*2+0] = inv2s2;
    prm[i*2+1] = AA;
    numer[i] = expf(-XX * inv2s2);
    float sp = log1pf(expf(0.3f - SC));
    atomicAdd(wsum + 1, sp * (1.0f / 1600.0f));
    int pos = atomicAdd(cnt + bp, 1);
    lst[bp * 1600 + pos] = i;
  }
}

// ---------------- K2b: MFMA dist^T fragments -> vectorized ushort4 stores ----------------
// Wave: j-range 32 (2 frags, A-operand) x i-range 64 (4 frags, B-operand).
__global__ __launch_bounds__(256) void k_cross(const ushort* __restrict__ Pb,
    const ushort* __restrict__ Ab, const float* __restrict__ prm,
    const int* __restrict__ cnt, const int* __restrict__ lst,
    ushort* __restrict__ distb) {
  int t = blockIdx.z;
  int n_t = min(cnt[t], 1600);
  int i0 = blockIdx.y * 64;
  if (i0 >= n_t) return;
  int j0 = blockIdx.x * 128;
  __shared__ int s_gis[64];
  int tid = threadIdx.x;
  if (tid < 64) {
    int gi = lst[t*1600 + min(i0 + tid, n_t - 1)];
    s_gis[tid] = min(max(gi, 0), NROW - 1);
  }
  __syncthreads();
  const int w = tid >> 6, lane = tid & 63, q = lane >> 4, m = lane & 15;
  const ushort* jp0 = Pb + ((size_t)(j0 + w*32 + m)*16 + t) * 256;
  const ushort* jp1 = jp0 + 16*16*256;   // +16 j rows
  const ushort* ip[4];
  #pragma unroll
  for (int it = 0; it < 4; it++) ip[it] = Ab + (size_t)s_gis[it*16 + m] * 256;
  f32x4 acc[2][4];
  #pragma unroll
  for (int jt = 0; jt < 2; jt++)
    #pragma unroll
    for (int it = 0; it < 4; it++) { f32x4 z = {0.f,0.f,0.f,0.f}; acc[jt][it] = z; }
  for (int k0 = 0; k0 < 256; k0 += 32) {
    bf16x8 jf0 = *(const bf16x8*)(jp0 + k0 + q*8);
    bf16x8 jf1 = *(const bf16x8*)(jp1 + k0 + q*8);
    #pragma unroll
    for (int it = 0; it < 4; it++) {
      bf16x8 af = *(const bf16x8*)(ip[it] + k0 + q*8);
      acc[0][it] = __builtin_amdgcn_mfma_f32_16x16x32_bf16(jf0, af, acc[0][it], 0, 0, 0);
      acc[1][it] = __builtin_amdgcn_mfma_f32_16x16x32_bf16(jf1, af, acc[1][it], 0, 0, 0);
    }
  }
  // D rows = j (4q+reg within jt tile), cols = i (m within it tile)
  #pragma unroll
  for (int jt = 0; jt < 2; jt++) {
    #pragma unroll
    for (int it = 0; it < 4; it++) {
      int iloc = it*16 + m;
      if (i0 + iloc < n_t) {
        int gi = s_gis[iloc];
        float inv2s2 = prm[gi*2], aa = prm[gi*2+1];
        int j = j0 + w*32 + jt*16 + 4*q;
        ushort4 o;
        o.x = f2bf(-(1.0f - 2.0f*acc[jt][it][0] + aa) * inv2s2);
        o.y = f2bf(-(1.0f - 2.0f*acc[jt][it][1] + aa) * inv2s2);
        o.z = f2bf(-(1.0f - 2.0f*acc[jt][it][2] + aa) * inv2s2);
        o.w = f2bf(-(1.0f - 2.0f*acc[jt][it][3] + aa) * inv2s2);
        *(ushort4*)(distb + (size_t)gi*NEG + j) = o;
      }
    }
  }
}

// ---------------- K3: top-5 via sorted-register merge, vectorized loads ----------------
__device__ __forceinline__ void sort5(float* c) {
  #define CE(i,j) { float hi = fmaxf(c[i], c[j]), lo = fminf(c[i], c[j]); c[i]=hi; c[j]=lo; }
  CE(0,1) CE(3,4) CE(2,4) CE(2,3) CE(1,4) CE(0,3) CE(0,2) CE(1,3) CE(1,2)
  #undef CE
}
__device__ __forceinline__ void ins5(float* t, float v) {
  float hi, lo;
  hi = fmaxf(t[0], v); lo = fminf(t[0], v); t[0] = hi; v = lo;
  hi = fmaxf(t[1], v); lo = fminf(t[1], v); t[1] = hi; v = lo;
  hi = fmaxf(t[2], v); lo = fminf(t[2], v); t[2] = hi; v = lo;
  hi = fmaxf(t[3], v); lo = fminf(t[3], v); t[3] = hi; v = lo;
  t[4] = fmaxf(t[4], v);
}
__global__ __launch_bounds__(256) void k_topk(const ushort* __restrict__ distb,
    const float* __restrict__ numer, float* __restrict__ wsum) {
  int i = blockIdx.x, tid = threadIdx.x;
  __shared__ float s_w[4][5];
  __shared__ float s_self;
  float t[5] = {-1e30f, -1e30f, -1e30f, -1e30f, -1e30f};
  const ushort* row = distb + (size_t)i * NEG;
  {
    int j = tid * 8;                      // 0..2047 (i < 1600 lives here)
    uint4 u = *(const uint4*)(row + j);
    unsigned ws0[4] = {u.x, u.y, u.z, u.w};
    #pragma unroll
    for (int e = 0; e < 4; e++) {
      float d0 = bf2f(ws0[e] & 0xffffu), d1 = bf2f(ws0[e] >> 16);
      int jj = j + e*2;
      if (jj == i) s_self = d0; else ins5(t, d0);
      if (jj + 1 == i) s_self = d1; else ins5(t, d1);
    }
  }
  if (tid < 144) {
    int j = 2048 + tid * 8;               // 2048..3199
    uint4 u = *(const uint4*)(row + j);
    unsigned ws1[4] = {u.x, u.y, u.z, u.w};
    #pragma unroll
    for (int e = 0; e < 4; e++) {
      ins5(t, bf2f(ws1[e] & 0xffffu));
      ins5(t, bf2f(ws1[e] >> 16));
    }
  }
  #pragma unroll
  for (int mk = 1; mk < 64; mk <<= 1) {
    float o[5], c[5];
    #pragma unroll
    for (int k = 0; k < 5; k++) o[k] = __shfl_xor(t[k], mk, 64);
    #pragma unroll
    for (int k = 0; k < 5; k++) c[k] = fmaxf(t[k], o[4 - k]);
    sort5(c);
    #pragma unroll
    for (int k = 0; k < 5; k++) t[k] = c[k];
  }
  if ((tid & 63) == 0)
    #pragma unroll
    for (int k = 0; k < 5; k++) s_w[tid >> 6][k] = t[k];
  __syncthreads();
  if (tid == 0) {
    #pragma unroll
    for (int wv = 1; wv < 4; wv++)
      #pragma unroll
      for (int k = 0; k < 5; k++) ins5(t, s_w[wv][k]);
    float deno = expf(s_self);
    #pragma unroll
    for (int k = 0; k < 5; k++) deno += expf(t[k]);
    atomicAdd(wsum + 0, (numer[i] / deno) * (1.0f / 1600.0f));
  }
}

// ---------------- K4: accumulators -> output ----------------
__global__ void k_final(const float* __restrict__ wsum, const int* __restrict__ flags,
                        void* __restrict__ out) {
  if (threadIdx.x == 0 && blockIdx.x == 0) {
    if (flags[0]) {
      ((float*)out)[0] = wsum[0];
      ((float*)out)[1] = wsum[1];
    } else {
      ushort* o = (ushort*)out;
      o[0] = f2bf(wsum[0]);
      o[1] = f2bf(wsum[1]);
    }
  }
}

extern "C" void kernel_launch(void* const* d_in, const int* in_sizes, int n_in,
                              void* d_out, int out_size, void* d_ws, size_t ws_size,
                              hipStream_t stream) {
  const ushort* fe0    = (const ushort*)d_in[0];
  const ushort* fe1    = (const ushort*)d_in[1];
  const ushort* W      = (const ushort*)d_in[2];
  const ushort* bias   = (const ushort*)d_in[3];
  const int*    bridge = (const int*)d_in[4];

  // workspace (~37.8 MB)
  ushort* Pb    = (ushort*)d_ws;             // 13,107,200
  ushort* Ab    = Pb + 13107200;             // 409,600
  ushort* Wt    = Ab + 409600;               // 65,536
  ushort* distb = Wt + 65536;                // 5,120,000
  float*  prm   = (float*)(distb + 5120000); // 3,200
  float*  numer = prm + 3200;                // 1,600
  float*  wsum  = numer + 1600;              // 4 floats, then cnt 16 ints (one memset)
  int*    cnt   = (int*)(wsum + 4);          // 16
  int*    lst   = cnt + 16;                  // 25,600
  int*    flags = lst + 25600;               // 4

  hipMemsetAsync(wsum, 0, 4*sizeof(float) + 16*sizeof(int), stream);

  k_detect<<<1, 64, 0, stream>>>(fe0, fe1, W, bias, flags);
  k_prepw <<<256, 256, 0, stream>>>(W, flags, Wt);
  k_proj  <<<800, 256, 0, stream>>>(fe0, fe1, Wt, bias, flags, Pb);
  k_bridge<<<1600, 256, 0, stream>>>(Pb, bridge, Ab, prm, numer, cnt, lst, wsum);
  k_cross <<<dim3(25, 8, 16), 256, 0, stream>>>(Pb, Ab, prm, cnt, lst, distb);
  k_topk  <<<1600, 256, 0, stream>>>(distb, numer, wsum);
  k_final <<<1, 64, 0, stream>>>(wsum, flags, d_out);
}

// Round 6
// 248.142 us; speedup vs baseline: 1.0167x; 1.0167x over previous
//
#include <hip/hip_runtime.h>
#include <hip/hip_bf16.h>

#define NROW 1600
#define NEG  3200
#define ROWS_FLAT 25600
#define NSPLIT 25        // 25 x 128 = 3200 j's

using bf16x8 = __attribute__((ext_vector_type(8))) short;
using f32x4  = __attribute__((ext_vector_type(4))) float;

__device__ __forceinline__ float bf2f(unsigned v) { return __uint_as_float(v << 16); }
__device__ __forceinline__ ushort f2bf(float f) {
  __hip_bfloat16 h = __float2bfloat16(f);
  return *(ushort*)&h;
}
__device__ __forceinline__ float load1(const ushort* p, size_t idx, int f32) {
  return f32 ? ((const float*)p)[idx] : bf2f(p[idx]);
}
__device__ __forceinline__ void load8(const ushort* p, size_t idx, int f32, float* o) {
  if (f32) {
    const float* q = (const float*)p;
    float4 a = *(const float4*)(q + idx);
    float4 b = *(const float4*)(q + idx + 4);
    o[0]=a.x; o[1]=a.y; o[2]=a.z; o[3]=a.w;
    o[4]=b.x; o[5]=b.y; o[6]=b.z; o[7]=b.w;
  } else {
    uint4 u = *(const uint4*)(p + idx);
    o[0]=bf2f(u.x & 0xffffu); o[1]=bf2f(u.x >> 16);
    o[2]=bf2f(u.y & 0xffffu); o[3]=bf2f(u.y >> 16);
    o[4]=bf2f(u.z & 0xffffu); o[5]=bf2f(u.z >> 16);
    o[6]=bf2f(u.w & 0xffffu); o[7]=bf2f(u.w >> 16);
  }
}
// wave-level dtype sniff: 1 = fp32, 0 = bf16. Reads ushorts 0..127 of buffer.
__device__ __forceinline__ int sniff_f32(const ushort* p, int lane) {
  unsigned e = ((unsigned)p[2*lane] >> 7) & 0xffu;
  unsigned long long b = __ballot(e >= 100u && e <= 140u);
  return (__popcll(b) >= 40) ? 0 : 1;
}

// ---------------- K0: Wt[n][k] = bf16(W[k][n]) (self-detects W dtype) ----------------
__global__ __launch_bounds__(256) void k_prepw(const ushort* __restrict__ W,
    ushort* __restrict__ Wt) {
  int fW = sniff_f32(W, threadIdx.x & 63);
  int n = blockIdx.x, k = threadIdx.x;
  Wt[n*256 + k] = f2bf(load1(W, (size_t)k*256 + n, fW));
}

// ---------------- K1: MFMA projection + L2 normalize ----------------
// Block: 64 rows x 256 cols; wave w owns cols w*64..w*64+63 (4 b-frags),
// all 64 rows (4 a-frags). Per k-step: 4 ds + 4 global + 16 MFMA.
__global__ __launch_bounds__(256) void k_proj(const ushort* __restrict__ fe0,
    const ushort* __restrict__ fe1, const ushort* __restrict__ Wt,
    const ushort* __restrict__ bias, ushort* __restrict__ Pb) {
  __shared__ union {
    ushort x[64*256];      // 32 KB swizzled A-tile: phys_k = k ^ ((r&7)<<3)
    ushort c[4][32*72];    // 18.4 KB per-half epilogue buffer (stride 72)
  } sh;
  __shared__ float s_ss[4][64];
  const int tid = threadIdx.x;
  const int w = tid >> 6, lane = tid & 63, q = lane >> 4, m = lane & 15;
  const int grow0 = blockIdx.x * 64;
  const int src1 = (grow0 >= ROWS_FLAT);
  const ushort* src = src1 ? fe1 : fe0;
  const size_t rbase = (size_t)(src1 ? grow0 - ROWS_FLAT : grow0) * 256;
  const int fSrc = sniff_f32(src, lane);
  const int fB   = sniff_f32(bias, lane);
  // stage 64 rows x 256 -> LDS
  if (!fSrc) {   // bf16 passthrough
    #pragma unroll
    for (int i = 0; i < 8; i++) {
      int l = tid + i*256;
      int r = l >> 5, kc = l & 31;
      uint4 u = *(const uint4*)(src + rbase + (size_t)r*256 + kc*8);
      *(uint4*)&sh.x[r*256 + ((kc*8) ^ ((r&7)<<3))] = u;
    }
  } else {       // fp32 convert path
    #pragma unroll
    for (int i = 0; i < 8; i++) {
      int l = tid + i*256;
      int r = l >> 5, kc = l & 31;
      float o[8];
      load8(src, rbase + (size_t)r*256 + kc*8, 1, o);
      uint4 u;
      u.x = (unsigned)f2bf(o[0]) | ((unsigned)f2bf(o[1]) << 16);
      u.y = (unsigned)f2bf(o[2]) | ((unsigned)f2bf(o[3]) << 16);
      u.z = (unsigned)f2bf(o[4]) | ((unsigned)f2bf(o[5]) << 16);
      u.w = (unsigned)f2bf(o[6]) | ((unsigned)f2bf(o[7]) << 16);
      *(uint4*)&sh.x[r*256 + ((kc*8) ^ ((r&7)<<3))] = u;
    }
  }
  __syncthreads();
  // acc[mt][nt]: rows mt*16+(4q+reg), cols w*64+nt*16+m ; init with bias
  f32x4 acc[4][4];
  #pragma unroll
  for (int nt = 0; nt < 4; nt++) {
    float bb = load1(bias, w*64 + nt*16 + m, fB);
    f32x4 v = {bb, bb, bb, bb};
    #pragma unroll
    for (int mt = 0; mt < 4; mt++) acc[mt][nt] = v;
  }
  const int sw = (m & 7) << 3;   // row swizzle (row = mt*16+m, (row&7)==(m&7))
  for (int k0 = 0; k0 < 256; k0 += 32) {
    int pk = (k0 + q*8) ^ sw;
    bf16x8 a[4];
    #pragma unroll
    for (int mt = 0; mt < 4; mt++) a[mt] = *(const bf16x8*)&sh.x[(mt*16 + m)*256 + pk];
    #pragma unroll
    for (int nt = 0; nt < 4; nt++) {
      bf16x8 b = *(const bf16x8*)(Wt + (size_t)(w*64 + nt*16 + m)*256 + k0 + q*8);
      #pragma unroll
      for (int mt = 0; mt < 4; mt++)
        acc[mt][nt] = __builtin_amdgcn_mfma_f32_16x16x32_bf16(a[mt], b, acc[mt][nt], 0, 0, 0);
    }
  }
  // cross-wave row-norm: partial ss per (mt,reg) over this wave's 64 cols
  float ssp[4][4];
  #pragma unroll
  for (int mt = 0; mt < 4; mt++)
    #pragma unroll
    for (int reg = 0; reg < 4; reg++) {
      float s = 0.f;
      #pragma unroll
      for (int nt = 0; nt < 4; nt++) { float v = acc[mt][nt][reg]; s += v*v; }
      ssp[mt][reg] = s;
    }
  #pragma unroll
  for (int mk = 1; mk < 16; mk <<= 1)
    #pragma unroll
    for (int mt = 0; mt < 4; mt++)
      #pragma unroll
      for (int reg = 0; reg < 4; reg++) ssp[mt][reg] += __shfl_xor(ssp[mt][reg], mk, 64);
  if (m == 0)
    #pragma unroll
    for (int mt = 0; mt < 4; mt++)
      #pragma unroll
      for (int reg = 0; reg < 4; reg++) s_ss[w][mt*16 + 4*q + reg] = ssp[mt][reg];
  __syncthreads();   // also retires A-tile before c-overlay
  float inv[4][4];
  #pragma unroll
  for (int mt = 0; mt < 4; mt++)
    #pragma unroll
    for (int reg = 0; reg < 4; reg++) {
      int row = mt*16 + 4*q + reg;
      float s = s_ss[0][row] + s_ss[1][row] + s_ss[2][row] + s_ss[3][row];
      inv[mt][reg] = 1.0f / sqrtf(s);
    }
  // two 32-row halves: park bf16 in wave-private c-buf, then vector stores
  #pragma unroll
  for (int half = 0; half < 2; half++) {
    #pragma unroll
    for (int mt = half*2; mt < half*2 + 2; mt++)
      #pragma unroll
      for (int reg = 0; reg < 4; reg++) {
        int rl = (mt - half*2)*16 + 4*q + reg;
        #pragma unroll
        for (int nt = 0; nt < 4; nt++)
          sh.c[w][rl*72 + nt*16 + m] = f2bf(acc[mt][nt][reg] * inv[mt][reg]);
      }
    int rl = (lane >> 3), c16 = lane & 7;    // 8 rows x 8 col-chunks per iter
    #pragma unroll
    for (int it = 0; it < 4; it++) {
      int row = it*8 + rl;
      int grow = grow0 + half*32 + row;
      int srcid = grow / ROWS_FLAT;
      int rem   = grow % ROWS_FLAT;
      int b  = rem / 1600;
      int t  = (rem / 100) & 15;
      int qq = rem % 100;
      size_t orow = ((size_t)(srcid*1600 + b*100 + qq) * 16 + t) * 256;
      uint4 v = *(uint4*)&sh.c[w][row*72 + c16*8];
      *(uint4*)(Pb + orow + w*64 + c16*8) = v;
    }
  }
}

// ---------------- K2: bridge prep (Ab bf16), numer, softplus, bucketing ----------------
__global__ __launch_bounds__(256) void k_bridge(const ushort* __restrict__ Pb,
    const int* __restrict__ bridge, ushort* __restrict__ Ab,
    float* __restrict__ prm, float* __restrict__ numer,
    int* __restrict__ cnt, int* __restrict__ lst, float* __restrict__ wsum) {
  int i = blockIdx.x, c = threadIdx.x;
  int bh = bridge[i*3+0], bp = bridge[i*3+1], bt = bridge[i*3+2];
  float bhf = (float)bh, bpf = (float)bp, btf = (float)bt;
  float alpha = (bpf - bhf) / (btf - bhf);
  float sigma = alpha * (btf - bpf);
  const ushort* base = Pb + (size_t)i * 16 * 256;
  float g0 = bf2f(base[bh*256 + c]), g1 = bf2f(base[bp*256 + c]), g2 = bf2f(base[bt*256 + c]);
  float head = bf2f(base[c]), tail = bf2f(base[15*256 + c]);
  float a = (1.0f - alpha) * g0 + alpha * g2;
  float x = g1 - a;
  Ab[(size_t)i*256 + c] = f2bf(a);
  float xx = x*x, aac = a*a, sc = head*tail;
  #pragma unroll
  for (int mk = 1; mk < 64; mk <<= 1) {
    xx  += __shfl_xor(xx, mk, 64);
    aac += __shfl_xor(aac, mk, 64);
    sc  += __shfl_xor(sc, mk, 64);
  }
  __shared__ float red[3][4];
  int wv = c >> 6;
  if ((c & 63) == 0) { red[0][wv]=xx; red[1][wv]=aac; red[2][wv]=sc; }
  __syncthreads();
  if (c == 0) {
    float XX = red[0][0]+red[0][1]+red[0][2]+red[0][3];
    float AA = red[1][0]+red[1][1]+red[1][2]+red[1][3];
    float SC = red[2][0]+red[2][1]+red[2][2]+red[2][3];
    float inv2s2 = 1.0f / (2.0f * sigma * sigma);
    prm[i*2+0] = inv2s2;
    prm[i*2+1] = AA;
    numer[i] = expf(-XX * inv2s2);
    float sp = log1pf(expf(0.3f - SC));
    atomicAdd(wsum + 1, sp * (1.0f / 1600.0f));
    int pos = atomicAdd(cnt + bp, 1);
    lst[bp * 1600 + pos] = i;
  }
}

// ---------------- top-5 helpers ----------------
__device__ __forceinline__ void sort5(float* c) {
  #define CE(i,j) { float hi = fmaxf(c[i], c[j]), lo = fminf(c[i], c[j]); c[i]=hi; c[j]=lo; }
  CE(0,1) CE(3,4) CE(2,4) CE(2,3) CE(1,4) CE(0,3) CE(0,2) CE(1,3) CE(1,2)
  #undef CE
}
__device__ __forceinline__ void ins5(float* t, float v) {
  float hi, lo;
  hi = fmaxf(t[0], v); lo = fminf(t[0], v); t[0] = hi; v = lo;
  hi = fmaxf(t[1], v); lo = fminf(t[1], v); t[1] = hi; v = lo;
  hi = fmaxf(t[2], v); lo = fminf(t[2], v); t[2] = hi; v = lo;
  hi = fmaxf(t[3], v); lo = fminf(t[3], v); t[3] = hi; v = lo;
  t[4] = fmaxf(t[4], v);
}

// ---------------- K3: fused dist + per-split top-5 ----------------
// Block: (j-split of 128) x (32 i's of one t-bucket). dist never materialized.
__global__ __launch_bounds__(256) void k_cross(const ushort* __restrict__ Pb,
    const ushort* __restrict__ Ab, const float* __restrict__ prm,
    const int* __restrict__ cnt, const int* __restrict__ lst,
    float* __restrict__ part) {
  int t = blockIdx.z;
  int n_t = min(cnt[t], 1600);
  int i0 = blockIdx.y * 32;
  if (i0 >= n_t) return;
  int j0 = blockIdx.x * 128;
  __shared__ int s_gis[32];
  __shared__ float s_red[4][32][6];
  int tid = threadIdx.x;
  if (tid < 32) {
    int gi = lst[t*1600 + min(i0 + tid, n_t - 1)];
    s_gis[tid] = min(max(gi, 0), NROW - 1);
  }
  __syncthreads();
  const int w = tid >> 6, lane = tid & 63, q = lane >> 4, m = lane & 15;
  const ushort* jp0 = Pb + ((size_t)(j0 + w*32 + m)*16 + t) * 256;
  const ushort* jp1 = jp0 + (size_t)16*16*256;
  int gi0 = s_gis[m], gi1 = s_gis[16 + m];
  const ushort* ip0 = Ab + (size_t)gi0 * 256;
  const ushort* ip1 = Ab + (size_t)gi1 * 256;
  f32x4 acc[2][2];   // [jt][it]
  #pragma unroll
  for (int jt = 0; jt < 2; jt++)
    #pragma unroll
    for (int it = 0; it < 2; it++) { f32x4 z = {0.f,0.f,0.f,0.f}; acc[jt][it] = z; }
  for (int k0 = 0; k0 < 256; k0 += 32) {
    bf16x8 jf0 = *(const bf16x8*)(jp0 + k0 + q*8);
    bf16x8 jf1 = *(const bf16x8*)(jp1 + k0 + q*8);
    bf16x8 if0 = *(const bf16x8*)(ip0 + k0 + q*8);
    bf16x8 if1 = *(const bf16x8*)(ip1 + k0 + q*8);
    acc[0][0] = __builtin_amdgcn_mfma_f32_16x16x32_bf16(jf0, if0, acc[0][0], 0, 0, 0);
    acc[0][1] = __builtin_amdgcn_mfma_f32_16x16x32_bf16(jf0, if1, acc[0][1], 0, 0, 0);
    acc[1][0] = __builtin_amdgcn_mfma_f32_16x16x32_bf16(jf1, if0, acc[1][0], 0, 0, 0);
    acc[1][1] = __builtin_amdgcn_mfma_f32_16x16x32_bf16(jf1, if1, acc[1][1], 0, 0, 0);
  }
  // per-lane top5/self per it-column. D: row(j) = 4q+reg (+jt*16), col(i) = m.
  float top[2][5], selfv[2] = {-1e30f, -1e30f};
  float p0i = prm[gi0*2], p0a = prm[gi0*2+1];
  float p1i = prm[gi1*2], p1a = prm[gi1*2+1];
  #pragma unroll
  for (int it = 0; it < 2; it++)
    #pragma unroll
    for (int k = 0; k < 5; k++) top[it][k] = -1e30f;
  #pragma unroll
  for (int jt = 0; jt < 2; jt++)
    #pragma unroll
    for (int reg = 0; reg < 4; reg++) {
      int j = j0 + w*32 + jt*16 + 4*q + reg;
      float d0 = -(1.0f - 2.0f*acc[jt][0][reg] + p0a) * p0i;
      float d1 = -(1.0f - 2.0f*acc[jt][1][reg] + p1a) * p1i;
      if (j == gi0) selfv[0] = d0; else ins5(top[0], d0);
      if (j == gi1) selfv[1] = d1; else ins5(top[1], d1);
    }
  // reduce over q (lane bits 4,5): bitonic 5-merge + self max
  #pragma unroll
  for (int mk = 16; mk <= 32; mk <<= 1) {
    #pragma unroll
    for (int it = 0; it < 2; it++) {
      float o[5], c[5];
      #pragma unroll
      for (int k = 0; k < 5; k++) o[k] = __shfl_xor(top[it][k], mk, 64);
      #pragma unroll
      for (int k = 0; k < 5; k++) c[k] = fmaxf(top[it][k], o[4 - k]);
      sort5(c);
      #pragma unroll
      for (int k = 0; k < 5; k++) top[it][k] = c[k];
      selfv[it] = fmaxf(selfv[it], __shfl_xor(selfv[it], mk, 64));
    }
  }
  if (q == 0) {
    #pragma unroll
    for (int it = 0; it < 2; it++) {
      #pragma unroll
      for (int k = 0; k < 5; k++) s_red[w][it*16 + m][k] = top[it][k];
      s_red[w][it*16 + m][5] = selfv[it];
    }
  }
  __syncthreads();
  if (tid < 32 && i0 + tid < n_t) {
    float T[5], S = s_red[0][tid][5];
    #pragma unroll
    for (int k = 0; k < 5; k++) T[k] = s_red[0][tid][k];
    #pragma unroll
    for (int w2 = 1; w2 < 4; w2++) {
      #pragma unroll
      for (int k = 0; k < 5; k++) ins5(T, s_red[w2][tid][k]);
      S = fmaxf(S, s_red[w2][tid][5]);
    }
    float* pp = part + ((size_t)s_gis[tid]*NSPLIT + blockIdx.x) * 6;
    #pragma unroll
    for (int k = 0; k < 5; k++) pp[k] = T[k];
    pp[5] = S;
  }
}

// ---------------- K4: single-block merge + final losses ----------------
__global__ __launch_bounds__(1024) void k_merge(const float* __restrict__ part,
    const float* __restrict__ numer, const float* __restrict__ wsum,
    const ushort* __restrict__ fe0, void* __restrict__ out) {
  __shared__ float s_sum[16];
  __shared__ int s_flag;
  int tid = threadIdx.x;
  if (tid < 64) {
    int f = sniff_f32(fe0, tid);
    if (tid == 0) s_flag = f;
  }
  float local = 0.f;
  for (int i = tid; i < NROW; i += 1024) {
    const float* pp = part + (size_t)i * NSPLIT * 6;
    float T[5]; float S = pp[5];
    #pragma unroll
    for (int k = 0; k < 5; k++) T[k] = pp[k];
    for (int s = 1; s < NSPLIT; s++) {
      const float* ps = pp + s*6;
      #pragma unroll
      for (int k = 0; k < 5; k++) ins5(T, ps[k]);
      S = fmaxf(S, ps[5]);
    }
    float deno = expf(S);
    #pragma unroll
    for (int k = 0; k < 5; k++) deno += expf(T[k]);
    local += numer[i] / deno;
  }
  #pragma unroll
  for (int mk = 1; mk < 64; mk <<= 1) local += __shfl_xor(local, mk, 64);
  if ((tid & 63) == 0) s_sum[tid >> 6] = local;
  __syncthreads();
  if (tid == 0) {
    float tot = 0.f;
    #pragma unroll
    for (int wv = 0; wv < 16; wv++) tot += s_sum[wv];
    float brown = tot * (1.0f / 1600.0f);
    float sp = wsum[1];
    if (s_flag) {
      ((float*)out)[0] = brown;
      ((float*)out)[1] = sp;
    } else {
      ushort* o = (ushort*)out;
      o[0] = f2bf(brown);
      o[1] = f2bf(sp);
    }
  }
}

extern "C" void kernel_launch(void* const* d_in, const int* in_sizes, int n_in,
                              void* d_out, int out_size, void* d_ws, size_t ws_size,
                              hipStream_t stream) {
  const ushort* fe0    = (const ushort*)d_in[0];
  const ushort* fe1    = (const ushort*)d_in[1];
  const ushort* W      = (const ushort*)d_in[2];
  const ushort* bias   = (const ushort*)d_in[3];
  const int*    bridge = (const int*)d_in[4];

  // workspace (~28.2 MB)
  ushort* Pb    = (ushort*)d_ws;               // 13,107,200
  ushort* Ab    = Pb + 13107200;               // 409,600
  ushort* Wt    = Ab + 409600;                 // 65,536
  float*  part  = (float*)(Wt + 65536);        // 1600*25*6 = 240,000
  float*  prm   = part + 240000;               // 3,200
  float*  numer = prm + 3200;                  // 1,600
  float*  wsum  = numer + 1600;                // 4
  int*    cnt   = (int*)(wsum + 4);            // 16
  int*    lst   = cnt + 16;                    // 25,600

  hipMemsetAsync(wsum, 0, 4*sizeof(float) + 16*sizeof(int), stream);

  k_prepw <<<256, 256, 0, stream>>>(W, Wt);
  k_proj  <<<800, 256, 0, stream>>>(fe0, fe1, Wt, bias, Pb);
  k_bridge<<<1600, 256, 0, stream>>>(Pb, bridge, Ab, prm, numer, cnt, lst, wsum);
  k_cross <<<dim3(NSPLIT, 13, 16), 256, 0, stream>>>(Pb, Ab, prm, cnt, lst, part);
  k_merge <<<1, 1024, 0, stream>>>(part, numer, wsum, fe0, d_out);
}

// Round 7
// 193.655 us; speedup vs baseline: 1.3027x; 1.2814x over previous
//
#include <hip/hip_runtime.h>
#include <hip/hip_bf16.h>

#define NROW 1600
#define NEG  3200
#define ROWS_FLAT 25600
#define NSPLIT 25        // 25 x 128 = 3200 j's

using bf16x8 = __attribute__((ext_vector_type(8))) short;
using f32x4  = __attribute__((ext_vector_type(4))) float;

__device__ __forceinline__ float bf2f(unsigned v) { return __uint_as_float(v << 16); }
__device__ __forceinline__ ushort f2bf(float f) {
  __hip_bfloat16 h = __float2bfloat16(f);
  return *(ushort*)&h;
}
__device__ __forceinline__ float load1(const ushort* p, size_t idx, int f32) {
  return f32 ? ((const float*)p)[idx] : bf2f(p[idx]);
}
__device__ __forceinline__ void load8(const ushort* p, size_t idx, int f32, float* o) {
  if (f32) {
    const float* q = (const float*)p;
    float4 a = *(const float4*)(q + idx);
    float4 b = *(const float4*)(q + idx + 4);
    o[0]=a.x; o[1]=a.y; o[2]=a.z; o[3]=a.w;
    o[4]=b.x; o[5]=b.y; o[6]=b.z; o[7]=b.w;
  } else {
    uint4 u = *(const uint4*)(p + idx);
    o[0]=bf2f(u.x & 0xffffu); o[1]=bf2f(u.x >> 16);
    o[2]=bf2f(u.y & 0xffffu); o[3]=bf2f(u.y >> 16);
    o[4]=bf2f(u.z & 0xffffu); o[5]=bf2f(u.z >> 16);
    o[6]=bf2f(u.w & 0xffffu); o[7]=bf2f(u.w >> 16);
  }
}
// wave-level dtype sniff: 1 = fp32, 0 = bf16. Reads ushorts 0..127 of buffer.
__device__ __forceinline__ int sniff_f32(const ushort* p, int lane) {
  unsigned e = ((unsigned)p[2*lane] >> 7) & 0xffu;
  unsigned long long b = __ballot(e >= 100u && e <= 140u);
  return (__popcll(b) >= 40) ? 0 : 1;
}

// ---------------- K0: Wt[n][k] = bf16(W[k][n]) (self-detects W dtype) ----------------
__global__ __launch_bounds__(256) void k_prepw(const ushort* __restrict__ W,
    ushort* __restrict__ Wt) {
  int fW = sniff_f32(W, threadIdx.x & 63);
  int n = blockIdx.x, k = threadIdx.x;
  Wt[n*256 + k] = f2bf(load1(W, (size_t)k*256 + n, fW));
}

// ---------------- K1: MFMA projection + L2 normalize ----------------
// Block: 64 rows x 256 cols; wave w owns cols w*64..w*64+63 (4 b-frags),
// all 64 rows (4 a-frags). Per k-step: 4 ds + 4 global + 16 MFMA.
__global__ __launch_bounds__(256) void k_proj(const ushort* __restrict__ fe0,
    const ushort* __restrict__ fe1, const ushort* __restrict__ Wt,
    const ushort* __restrict__ bias, ushort* __restrict__ Pb) {
  __shared__ union {
    ushort x[64*256];      // 32 KB swizzled A-tile: phys_k = k ^ ((r&7)<<3)
    ushort c[4][32*72];    // 18.4 KB per-half epilogue buffer (stride 72)
  } sh;
  __shared__ float s_ss[4][64];
  const int tid = threadIdx.x;
  const int w = tid >> 6, lane = tid & 63, q = lane >> 4, m = lane & 15;
  const int grow0 = blockIdx.x * 64;
  const int src1 = (grow0 >= ROWS_FLAT);
  const ushort* src = src1 ? fe1 : fe0;
  const size_t rbase = (size_t)(src1 ? grow0 - ROWS_FLAT : grow0) * 256;
  const int fSrc = sniff_f32(src, lane);
  const int fB   = sniff_f32(bias, lane);
  // stage 64 rows x 256 -> LDS
  if (!fSrc) {   // bf16 passthrough
    #pragma unroll
    for (int i = 0; i < 8; i++) {
      int l = tid + i*256;
      int r = l >> 5, kc = l & 31;
      uint4 u = *(const uint4*)(src + rbase + (size_t)r*256 + kc*8);
      *(uint4*)&sh.x[r*256 + ((kc*8) ^ ((r&7)<<3))] = u;
    }
  } else {       // fp32 convert path
    #pragma unroll
    for (int i = 0; i < 8; i++) {
      int l = tid + i*256;
      int r = l >> 5, kc = l & 31;
      float o[8];
      load8(src, rbase + (size_t)r*256 + kc*8, 1, o);
      uint4 u;
      u.x = (unsigned)f2bf(o[0]) | ((unsigned)f2bf(o[1]) << 16);
      u.y = (unsigned)f2bf(o[2]) | ((unsigned)f2bf(o[3]) << 16);
      u.z = (unsigned)f2bf(o[4]) | ((unsigned)f2bf(o[5]) << 16);
      u.w = (unsigned)f2bf(o[6]) | ((unsigned)f2bf(o[7]) << 16);
      *(uint4*)&sh.x[r*256 + ((kc*8) ^ ((r&7)<<3))] = u;
    }
  }
  __syncthreads();
  // acc[mt][nt]: rows mt*16+(4q+reg), cols w*64+nt*16+m ; init with bias
  f32x4 acc[4][4];
  #pragma unroll
  for (int nt = 0; nt < 4; nt++) {
    float bb = load1(bias, w*64 + nt*16 + m, fB);
    f32x4 v = {bb, bb, bb, bb};
    #pragma unroll
    for (int mt = 0; mt < 4; mt++) acc[mt][nt] = v;
  }
  const int sw = (m & 7) << 3;   // row swizzle (row = mt*16+m, (row&7)==(m&7))
  for (int k0 = 0; k0 < 256; k0 += 32) {
    int pk = (k0 + q*8) ^ sw;
    bf16x8 a[4];
    #pragma unroll
    for (int mt = 0; mt < 4; mt++) a[mt] = *(const bf16x8*)&sh.x[(mt*16 + m)*256 + pk];
    #pragma unroll
    for (int nt = 0; nt < 4; nt++) {
      bf16x8 b = *(const bf16x8*)(Wt + (size_t)(w*64 + nt*16 + m)*256 + k0 + q*8);
      #pragma unroll
      for (int mt = 0; mt < 4; mt++)
        acc[mt][nt] = __builtin_amdgcn_mfma_f32_16x16x32_bf16(a[mt], b, acc[mt][nt], 0, 0, 0);
    }
  }
  // cross-wave row-norm: partial ss per (mt,reg) over this wave's 64 cols
  float ssp[4][4];
  #pragma unroll
  for (int mt = 0; mt < 4; mt++)
    #pragma unroll
    for (int reg = 0; reg < 4; reg++) {
      float s = 0.f;
      #pragma unroll
      for (int nt = 0; nt < 4; nt++) { float v = acc[mt][nt][reg]; s += v*v; }
      ssp[mt][reg] = s;
    }
  #pragma unroll
  for (int mk = 1; mk < 16; mk <<= 1)
    #pragma unroll
    for (int mt = 0; mt < 4; mt++)
      #pragma unroll
      for (int reg = 0; reg < 4; reg++) ssp[mt][reg] += __shfl_xor(ssp[mt][reg], mk, 64);
  if (m == 0)
    #pragma unroll
    for (int mt = 0; mt < 4; mt++)
      #pragma unroll
      for (int reg = 0; reg < 4; reg++) s_ss[w][mt*16 + 4*q + reg] = ssp[mt][reg];
  __syncthreads();   // also retires A-tile before c-overlay
  float inv[4][4];
  #pragma unroll
  for (int mt = 0; mt < 4; mt++)
    #pragma unroll
    for (int reg = 0; reg < 4; reg++) {
      int row = mt*16 + 4*q + reg;
      float s = s_ss[0][row] + s_ss[1][row] + s_ss[2][row] + s_ss[3][row];
      inv[mt][reg] = 1.0f / sqrtf(s);
    }
  // two 32-row halves: park bf16 in wave-private c-buf, then vector stores
  #pragma unroll
  for (int half = 0; half < 2; half++) {
    #pragma unroll
    for (int mt = half*2; mt < half*2 + 2; mt++)
      #pragma unroll
      for (int reg = 0; reg < 4; reg++) {
        int rl = (mt - half*2)*16 + 4*q + reg;
        #pragma unroll
        for (int nt = 0; nt < 4; nt++)
          sh.c[w][rl*72 + nt*16 + m] = f2bf(acc[mt][nt][reg] * inv[mt][reg]);
      }
    int rl = (lane >> 3), c16 = lane & 7;    // 8 rows x 8 col-chunks per iter
    #pragma unroll
    for (int it = 0; it < 4; it++) {
      int row = it*8 + rl;
      int grow = grow0 + half*32 + row;
      int srcid = grow / ROWS_FLAT;
      int rem   = grow % ROWS_FLAT;
      int b  = rem / 1600;
      int t  = (rem / 100) & 15;
      int qq = rem % 100;
      size_t orow = ((size_t)(srcid*1600 + b*100 + qq) * 16 + t) * 256;
      uint4 v = *(uint4*)&sh.c[w][row*72 + c16*8];
      *(uint4*)(Pb + orow + w*64 + c16*8) = v;
    }
  }
}

// ---------------- K2: bridge prep (Ab bf16), numer, softplus, bucketing ----------------
__global__ __launch_bounds__(256) void k_bridge(const ushort* __restrict__ Pb,
    const int* __restrict__ bridge, ushort* __restrict__ Ab,
    float* __restrict__ prm, float* __restrict__ numer,
    int* __restrict__ cnt, int* __restrict__ lst, float* __restrict__ wsum) {
  int i = blockIdx.x, c = threadIdx.x;
  int bh = bridge[i*3+0], bp = bridge[i*3+1], bt = bridge[i*3+2];
  float bhf = (float)bh, bpf = (float)bp, btf = (float)bt;
  float alpha = (bpf - bhf) / (btf - bhf);
  float sigma = alpha * (btf - bpf);
  const ushort* base = Pb + (size_t)i * 16 * 256;
  float g0 = bf2f(base[bh*256 + c]), g1 = bf2f(base[bp*256 + c]), g2 = bf2f(base[bt*256 + c]);
  float head = bf2f(base[c]), tail = bf2f(base[15*256 + c]);
  float a = (1.0f - alpha) * g0 + alpha * g2;
  float x = g1 - a;
  Ab[(size_t)i*256 + c] = f2bf(a);
  float xx = x*x, aac = a*a, sc = head*tail;
  #pragma unroll
  for (int mk = 1; mk < 64; mk <<= 1) {
    xx  += __shfl_xor(xx, mk, 64);
    aac += __shfl_xor(aac, mk, 64);
    sc  += __shfl_xor(sc, mk, 64);
  }
  __shared__ float red[3][4];
  int wv = c >> 6;
  if ((c & 63) == 0) { red[0][wv]=xx; red[1][wv]=aac; red[2][wv]=sc; }
  __syncthreads();
  if (c == 0) {
    float XX = red[0][0]+red[0][1]+red[0][2]+red[0][3];
    float AA = red[1][0]+red[1][1]+red[1][2]+red[1][3];
    float SC = red[2][0]+red[2][1]+red[2][2]+red[2][3];
    float inv2s2 = 1.0f / (2.0f * sigma * sigma);
    prm[i*2+0] = inv2s2;
    prm[i*2+1] = AA;
    numer[i] = expf(-XX * inv2s2);
    float sp = log1pf(expf(0.3f - SC));
    atomicAdd(wsum + 1, sp * (1.0f / 1600.0f));
    int pos = atomicAdd(cnt + bp, 1);
    lst[bp * 1600 + pos] = i;
  }
}

// ---------------- top-5 helpers ----------------
__device__ __forceinline__ void sort5(float* c) {
  #define CE(i,j) { float hi = fmaxf(c[i], c[j]), lo = fminf(c[i], c[j]); c[i]=hi; c[j]=lo; }
  CE(0,1) CE(3,4) CE(2,4) CE(2,3) CE(1,4) CE(0,3) CE(0,2) CE(1,3) CE(1,2)
  #undef CE
}
__device__ __forceinline__ void ins5(float* t, float v) {
  float hi, lo;
  hi = fmaxf(t[0], v); lo = fminf(t[0], v); t[0] = hi; v = lo;
  hi = fmaxf(t[1], v); lo = fminf(t[1], v); t[1] = hi; v = lo;
  hi = fmaxf(t[2], v); lo = fminf(t[2], v); t[2] = hi; v = lo;
  hi = fmaxf(t[3], v); lo = fminf(t[3], v); t[3] = hi; v = lo;
  t[4] = fmaxf(t[4], v);
}

// ---------------- K3: fused dist + per-split top-5 ----------------
// Block: (j-split of 128) x (32 i's of one t-bucket). dist never materialized.
__global__ __launch_bounds__(256) void k_cross(const ushort* __restrict__ Pb,
    const ushort* __restrict__ Ab, const float* __restrict__ prm,
    const int* __restrict__ cnt, const int* __restrict__ lst,
    float* __restrict__ part) {
  int t = blockIdx.z;
  int n_t = min(cnt[t], 1600);
  int i0 = blockIdx.y * 32;
  if (i0 >= n_t) return;
  int j0 = blockIdx.x * 128;
  __shared__ int s_gis[32];
  __shared__ float s_red[4][32][6];
  int tid = threadIdx.x;
  if (tid < 32) {
    int gi = lst[t*1600 + min(i0 + tid, n_t - 1)];
    s_gis[tid] = min(max(gi, 0), NROW - 1);
  }
  __syncthreads();
  const int w = tid >> 6, lane = tid & 63, q = lane >> 4, m = lane & 15;
  const ushort* jp0 = Pb + ((size_t)(j0 + w*32 + m)*16 + t) * 256;
  const ushort* jp1 = jp0 + (size_t)16*16*256;
  int gi0 = s_gis[m], gi1 = s_gis[16 + m];
  const ushort* ip0 = Ab + (size_t)gi0 * 256;
  const ushort* ip1 = Ab + (size_t)gi1 * 256;
  f32x4 acc[2][2];   // [jt][it]
  #pragma unroll
  for (int jt = 0; jt < 2; jt++)
    #pragma unroll
    for (int it = 0; it < 2; it++) { f32x4 z = {0.f,0.f,0.f,0.f}; acc[jt][it] = z; }
  for (int k0 = 0; k0 < 256; k0 += 32) {
    bf16x8 jf0 = *(const bf16x8*)(jp0 + k0 + q*8);
    bf16x8 jf1 = *(const bf16x8*)(jp1 + k0 + q*8);
    bf16x8 if0 = *(const bf16x8*)(ip0 + k0 + q*8);
    bf16x8 if1 = *(const bf16x8*)(ip1 + k0 + q*8);
    acc[0][0] = __builtin_amdgcn_mfma_f32_16x16x32_bf16(jf0, if0, acc[0][0], 0, 0, 0);
    acc[0][1] = __builtin_amdgcn_mfma_f32_16x16x32_bf16(jf0, if1, acc[0][1], 0, 0, 0);
    acc[1][0] = __builtin_amdgcn_mfma_f32_16x16x32_bf16(jf1, if0, acc[1][0], 0, 0, 0);
    acc[1][1] = __builtin_amdgcn_mfma_f32_16x16x32_bf16(jf1, if1, acc[1][1], 0, 0, 0);
  }
  // per-lane top5/self per it-column. D: row(j) = 4q+reg (+jt*16), col(i) = m.
  float top[2][5], selfv[2] = {-1e30f, -1e30f};
  float p0i = prm[gi0*2], p0a = prm[gi0*2+1];
  float p1i = prm[gi1*2], p1a = prm[gi1*2+1];
  #pragma unroll
  for (int it = 0; it < 2; it++)
    #pragma unroll
    for (int k = 0; k < 5; k++) top[it][k] = -1e30f;
  #pragma unroll
  for (int jt = 0; jt < 2; jt++)
    #pragma unroll
    for (int reg = 0; reg < 4; reg++) {
      int j = j0 + w*32 + jt*16 + 4*q + reg;
      float d0 = -(1.0f - 2.0f*acc[jt][0][reg] + p0a) * p0i;
      float d1 = -(1.0f - 2.0f*acc[jt][1][reg] + p1a) * p1i;
      if (j == gi0) selfv[0] = d0; else ins5(top[0], d0);
      if (j == gi1) selfv[1] = d1; else ins5(top[1], d1);
    }
  // reduce over q (lane bits 4,5): bitonic 5-merge + self max
  #pragma unroll
  for (int mk = 16; mk <= 32; mk <<= 1) {
    #pragma unroll
    for (int it = 0; it < 2; it++) {
      float o[5], c[5];
      #pragma unroll
      for (int k = 0; k < 5; k++) o[k] = __shfl_xor(top[it][k], mk, 64);
      #pragma unroll
      for (int k = 0; k < 5; k++) c[k] = fmaxf(top[it][k], o[4 - k]);
      sort5(c);
      #pragma unroll
      for (int k = 0; k < 5; k++) top[it][k] = c[k];
      selfv[it] = fmaxf(selfv[it], __shfl_xor(selfv[it], mk, 64));
    }
  }
  if (q == 0) {
    #pragma unroll
    for (int it = 0; it < 2; it++) {
      #pragma unroll
      for (int k = 0; k < 5; k++) s_red[w][it*16 + m][k] = top[it][k];
      s_red[w][it*16 + m][5] = selfv[it];
    }
  }
  __syncthreads();
  if (tid < 32 && i0 + tid < n_t) {
    float T[5], S = s_red[0][tid][5];
    #pragma unroll
    for (int k = 0; k < 5; k++) T[k] = s_red[0][tid][k];
    #pragma unroll
    for (int w2 = 1; w2 < 4; w2++) {
      #pragma unroll
      for (int k = 0; k < 5; k++) ins5(T, s_red[w2][tid][k]);
      S = fmaxf(S, s_red[w2][tid][5]);
    }
    float* pp = part + ((size_t)s_gis[tid]*NSPLIT + blockIdx.x) * 6;
    #pragma unroll
    for (int k = 0; k < 5; k++) pp[k] = T[k];
    pp[5] = S;
  }
}

// ---------------- K4: parallel merge (one row per thread, 25 blocks) ----------------
__global__ __launch_bounds__(64) void k_merge(const float* __restrict__ part,
    const float* __restrict__ numer, float* __restrict__ wsum) {
  int i = blockIdx.x * 64 + threadIdx.x;     // 25 blocks x 64 = 1600
  const float* pp = part + (size_t)i * NSPLIT * 6;
  float T[5]; float S = pp[5];
  #pragma unroll
  for (int k = 0; k < 5; k++) T[k] = pp[k];
  #pragma unroll
  for (int s = 1; s < NSPLIT; s++) {
    const float* ps = pp + s*6;
    float v0 = ps[0], v1 = ps[1], v2 = ps[2], v3 = ps[3], v4 = ps[4], v5 = ps[5];
    ins5(T, v0); ins5(T, v1); ins5(T, v2); ins5(T, v3); ins5(T, v4);
    S = fmaxf(S, v5);
  }
  float deno = expf(S);
  #pragma unroll
  for (int k = 0; k < 5; k++) deno += expf(T[k]);
  float local = numer[i] / deno;
  #pragma unroll
  for (int mk = 1; mk < 64; mk <<= 1) local += __shfl_xor(local, mk, 64);
  if (threadIdx.x == 0) atomicAdd(wsum + 0, local * (1.0f / 1600.0f));
}

// ---------------- K5: output write (dtype per sniff) ----------------
__global__ void k_out(const float* __restrict__ wsum, const ushort* __restrict__ fe0,
                      void* __restrict__ out) {
  int lane = threadIdx.x & 63;
  int f = sniff_f32(fe0, lane);
  if (lane == 0) {
    if (f) {
      ((float*)out)[0] = wsum[0];
      ((float*)out)[1] = wsum[1];
    } else {
      ushort* o = (ushort*)out;
      o[0] = f2bf(wsum[0]);
      o[1] = f2bf(wsum[1]);
    }
  }
}

extern "C" void kernel_launch(void* const* d_in, const int* in_sizes, int n_in,
                              void* d_out, int out_size, void* d_ws, size_t ws_size,
                              hipStream_t stream) {
  const ushort* fe0    = (const ushort*)d_in[0];
  const ushort* fe1    = (const ushort*)d_in[1];
  const ushort* W      = (const ushort*)d_in[2];
  const ushort* bias   = (const ushort*)d_in[3];
  const int*    bridge = (const int*)d_in[4];

  // workspace (~28.2 MB)
  ushort* Pb    = (ushort*)d_ws;               // 13,107,200
  ushort* Ab    = Pb + 13107200;               // 409,600
  ushort* Wt    = Ab + 409600;                 // 65,536
  float*  part  = (float*)(Wt + 65536);        // 1600*25*6 = 240,000
  float*  prm   = part + 240000;               // 3,200
  float*  numer = prm + 3200;                  // 1,600
  float*  wsum  = numer + 1600;                // 4
  int*    cnt   = (int*)(wsum + 4);            // 16
  int*    lst   = cnt + 16;                    // 25,600

  hipMemsetAsync(wsum, 0, 4*sizeof(float) + 16*sizeof(int), stream);

  k_prepw <<<256, 256, 0, stream>>>(W, Wt);
  k_proj  <<<800, 256, 0, stream>>>(fe0, fe1, Wt, bias, Pb);
  k_bridge<<<1600, 256, 0, stream>>>(Pb, bridge, Ab, prm, numer, cnt, lst, wsum);
  k_cross <<<dim3(NSPLIT, 13, 16), 256, 0, stream>>>(Pb, Ab, prm, cnt, lst, part);
  k_merge <<<25, 64, 0, stream>>>(part, numer, wsum);
  k_out   <<<1, 64, 0, stream>>>(wsum, fe0, d_out);
}

// Round 8
// 191.676 us; speedup vs baseline: 1.3162x; 1.0103x over previous
//
#include <hip/hip_runtime.h>
#include <hip/hip_bf16.h>

#define NROW 1600
#define NEG  3200
#define ROWS_FLAT 25600
#define NSPLIT 25        // 25 x 128 = 3200 j's

using bf16x8 = __attribute__((ext_vector_type(8))) short;
using f32x4  = __attribute__((ext_vector_type(4))) float;

__device__ __forceinline__ float bf2f(unsigned v) { return __uint_as_float(v << 16); }
__device__ __forceinline__ ushort f2bf(float f) {
  __hip_bfloat16 h = __float2bfloat16(f);
  return *(ushort*)&h;
}
__device__ __forceinline__ float load1(const ushort* p, size_t idx, int f32) {
  return f32 ? ((const float*)p)[idx] : bf2f(p[idx]);
}
__device__ __forceinline__ void load8(const ushort* p, size_t idx, int f32, float* o) {
  if (f32) {
    const float* q = (const float*)p;
    float4 a = *(const float4*)(q + idx);
    float4 b = *(const float4*)(q + idx + 4);
    o[0]=a.x; o[1]=a.y; o[2]=a.z; o[3]=a.w;
    o[4]=b.x; o[5]=b.y; o[6]=b.z; o[7]=b.w;
  } else {
    uint4 u = *(const uint4*)(p + idx);
    o[0]=bf2f(u.x & 0xffffu); o[1]=bf2f(u.x >> 16);
    o[2]=bf2f(u.y & 0xffffu); o[3]=bf2f(u.y >> 16);
    o[4]=bf2f(u.z & 0xffffu); o[5]=bf2f(u.z >> 16);
    o[6]=bf2f(u.w & 0xffffu); o[7]=bf2f(u.w >> 16);
  }
}
// wave-level dtype sniff: 1 = fp32, 0 = bf16. Reads ushorts 0..127 of buffer.
__device__ __forceinline__ int sniff_f32(const ushort* p, int lane) {
  unsigned e = ((unsigned)p[2*lane] >> 7) & 0xffu;
  unsigned long long b = __ballot(e >= 100u && e <= 140u);
  return (__popcll(b) >= 40) ? 0 : 1;
}

// ---------------- K0: Wt[n][k] = bf16(W[k][n]) + zero accumulators ----------------
__global__ __launch_bounds__(256) void k_prepw(const ushort* __restrict__ W,
    ushort* __restrict__ Wt, int* __restrict__ zbase) {
  if (blockIdx.x == 0 && threadIdx.x < 21) zbase[threadIdx.x] = 0;  // wsum[4]+cnt[16]+done[1]
  int fW = sniff_f32(W, threadIdx.x & 63);
  int n = blockIdx.x, k = threadIdx.x;
  Wt[n*256 + k] = f2bf(load1(W, (size_t)k*256 + n, fW));
}

// ---------------- K1: MFMA projection + L2 normalize (pipelined k-loop) ----------------
// Block: 64 rows x 256 cols; wave w owns cols w*64..w*64+63 (4 b-frags),
// all 64 rows (4 a-frags). Register double-buffer prefetch of A (LDS) and B (L2).
__global__ __launch_bounds__(256) void k_proj(const ushort* __restrict__ fe0,
    const ushort* __restrict__ fe1, const ushort* __restrict__ Wt,
    const ushort* __restrict__ bias, ushort* __restrict__ Pb) {
  __shared__ union {
    ushort x[64*256];      // 32 KB swizzled A-tile: phys_k = k ^ ((r&7)<<3)
    ushort c[4][32*72];    // 18.4 KB per-half epilogue buffer (stride 72)
  } sh;
  __shared__ float s_ss[4][64];
  const int tid = threadIdx.x;
  const int w = tid >> 6, lane = tid & 63, q = lane >> 4, m = lane & 15;
  const int grow0 = blockIdx.x * 64;
  const int src1 = (grow0 >= ROWS_FLAT);
  const ushort* src = src1 ? fe1 : fe0;
  const size_t rbase = (size_t)(src1 ? grow0 - ROWS_FLAT : grow0) * 256;
  const int fSrc = sniff_f32(src, lane);
  const int fB   = sniff_f32(bias, lane);
  // stage 64 rows x 256 -> LDS
  if (!fSrc) {   // bf16 passthrough
    #pragma unroll
    for (int i = 0; i < 8; i++) {
      int l = tid + i*256;
      int r = l >> 5, kc = l & 31;
      uint4 u = *(const uint4*)(src + rbase + (size_t)r*256 + kc*8);
      *(uint4*)&sh.x[r*256 + ((kc*8) ^ ((r&7)<<3))] = u;
    }
  } else {       // fp32 convert path
    #pragma unroll
    for (int i = 0; i < 8; i++) {
      int l = tid + i*256;
      int r = l >> 5, kc = l & 31;
      float o[8];
      load8(src, rbase + (size_t)r*256 + kc*8, 1, o);
      uint4 u;
      u.x = (unsigned)f2bf(o[0]) | ((unsigned)f2bf(o[1]) << 16);
      u.y = (unsigned)f2bf(o[2]) | ((unsigned)f2bf(o[3]) << 16);
      u.z = (unsigned)f2bf(o[4]) | ((unsigned)f2bf(o[5]) << 16);
      u.w = (unsigned)f2bf(o[6]) | ((unsigned)f2bf(o[7]) << 16);
      *(uint4*)&sh.x[r*256 + ((kc*8) ^ ((r&7)<<3))] = u;
    }
  }
  __syncthreads();
  // acc[mt][nt]: rows mt*16+(4q+reg), cols w*64+nt*16+m ; init with bias
  f32x4 acc[4][4];
  #pragma unroll
  for (int nt = 0; nt < 4; nt++) {
    float bb = load1(bias, w*64 + nt*16 + m, fB);
    f32x4 v = {bb, bb, bb, bb};
    #pragma unroll
    for (int mt = 0; mt < 4; mt++) acc[mt][nt] = v;
  }
  const int sw = (m & 7) << 3;   // row swizzle (row = mt*16+m, (row&7)==(m&7))
  const ushort* wbase = Wt + (size_t)(w*64 + m)*256 + q*8;
  // software-pipelined k-loop: prefetch k+1 fragments before k's MFMAs
  bf16x8 a_cur[4], b_cur[4];
  #pragma unroll
  for (int mt = 0; mt < 4; mt++)
    a_cur[mt] = *(const bf16x8*)&sh.x[(mt*16 + m)*256 + ((q*8) ^ sw)];
  #pragma unroll
  for (int nt = 0; nt < 4; nt++)
    b_cur[nt] = *(const bf16x8*)(wbase + (size_t)nt*16*256);
  #pragma unroll
  for (int k = 0; k < 8; k++) {
    bf16x8 a_nxt[4], b_nxt[4];
    if (k < 7) {
      int k0 = (k + 1) * 32;
      #pragma unroll
      for (int nt = 0; nt < 4; nt++)
        b_nxt[nt] = *(const bf16x8*)(wbase + (size_t)nt*16*256 + k0);
      int pk = (k0 + q*8) ^ sw;
      #pragma unroll
      for (int mt = 0; mt < 4; mt++)
        a_nxt[mt] = *(const bf16x8*)&sh.x[(mt*16 + m)*256 + pk];
    }
    #pragma unroll
    for (int nt = 0; nt < 4; nt++)
      #pragma unroll
      for (int mt = 0; mt < 4; mt++)
        acc[mt][nt] = __builtin_amdgcn_mfma_f32_16x16x32_bf16(a_cur[mt], b_cur[nt], acc[mt][nt], 0, 0, 0);
    if (k < 7) {
      #pragma unroll
      for (int x = 0; x < 4; x++) { a_cur[x] = a_nxt[x]; b_cur[x] = b_nxt[x]; }
    }
  }
  // cross-wave row-norm: partial ss per (mt,reg) over this wave's 64 cols
  float ssp[4][4];
  #pragma unroll
  for (int mt = 0; mt < 4; mt++)
    #pragma unroll
    for (int reg = 0; reg < 4; reg++) {
      float s = 0.f;
      #pragma unroll
      for (int nt = 0; nt < 4; nt++) { float v = acc[mt][nt][reg]; s += v*v; }
      ssp[mt][reg] = s;
    }
  #pragma unroll
  for (int mk = 1; mk < 16; mk <<= 1)
    #pragma unroll
    for (int mt = 0; mt < 4; mt++)
      #pragma unroll
      for (int reg = 0; reg < 4; reg++) ssp[mt][reg] += __shfl_xor(ssp[mt][reg], mk, 64);
  if (m == 0)
    #pragma unroll
    for (int mt = 0; mt < 4; mt++)
      #pragma unroll
      for (int reg = 0; reg < 4; reg++) s_ss[w][mt*16 + 4*q + reg] = ssp[mt][reg];
  __syncthreads();   // also retires A-tile before c-overlay
  float inv[4][4];
  #pragma unroll
  for (int mt = 0; mt < 4; mt++)
    #pragma unroll
    for (int reg = 0; reg < 4; reg++) {
      int row = mt*16 + 4*q + reg;
      float s = s_ss[0][row] + s_ss[1][row] + s_ss[2][row] + s_ss[3][row];
      inv[mt][reg] = 1.0f / sqrtf(s);
    }
  // two 32-row halves: park bf16 in wave-private c-buf, then vector stores
  #pragma unroll
  for (int half = 0; half < 2; half++) {
    #pragma unroll
    for (int mt = half*2; mt < half*2 + 2; mt++)
      #pragma unroll
      for (int reg = 0; reg < 4; reg++) {
        int rl = (mt - half*2)*16 + 4*q + reg;
        #pragma unroll
        for (int nt = 0; nt < 4; nt++)
          sh.c[w][rl*72 + nt*16 + m] = f2bf(acc[mt][nt][reg] * inv[mt][reg]);
      }
    int rl = (lane >> 3), c16 = lane & 7;    // 8 rows x 8 col-chunks per iter
    #pragma unroll
    for (int it = 0; it < 4; it++) {
      int row = it*8 + rl;
      int grow = grow0 + half*32 + row;
      int srcid = grow / ROWS_FLAT;
      int rem   = grow % ROWS_FLAT;
      int b  = rem / 1600;
      int t  = (rem / 100) & 15;
      int qq = rem % 100;
      size_t orow = ((size_t)(srcid*1600 + b*100 + qq) * 16 + t) * 256;
      uint4 v = *(uint4*)&sh.c[w][row*72 + c16*8];
      *(uint4*)(Pb + orow + w*64 + c16*8) = v;
    }
  }
}

// ---------------- K2: bridge prep (Ab bf16), numer, softplus, bucketing ----------------
__global__ __launch_bounds__(256) void k_bridge(const ushort* __restrict__ Pb,
    const int* __restrict__ bridge, ushort* __restrict__ Ab,
    float* __restrict__ prm, float* __restrict__ numer,
    int* __restrict__ cnt, int* __restrict__ lst, float* __restrict__ wsum) {
  int i = blockIdx.x, c = threadIdx.x;
  int bh = bridge[i*3+0], bp = bridge[i*3+1], bt = bridge[i*3+2];
  float bhf = (float)bh, bpf = (float)bp, btf = (float)bt;
  float alpha = (bpf - bhf) / (btf - bhf);
  float sigma = alpha * (btf - bpf);
  const ushort* base = Pb + (size_t)i * 16 * 256;
  float g0 = bf2f(base[bh*256 + c]), g1 = bf2f(base[bp*256 + c]), g2 = bf2f(base[bt*256 + c]);
  float head = bf2f(base[c]), tail = bf2f(base[15*256 + c]);
  float a = (1.0f - alpha) * g0 + alpha * g2;
  float x = g1 - a;
  Ab[(size_t)i*256 + c] = f2bf(a);
  float xx = x*x, aac = a*a, sc = head*tail;
  #pragma unroll
  for (int mk = 1; mk < 64; mk <<= 1) {
    xx  += __shfl_xor(xx, mk, 64);
    aac += __shfl_xor(aac, mk, 64);
    sc  += __shfl_xor(sc, mk, 64);
  }
  __shared__ float red[3][4];
  int wv = c >> 6;
  if ((c & 63) == 0) { red[0][wv]=xx; red[1][wv]=aac; red[2][wv]=sc; }
  __syncthreads();
  if (c == 0) {
    float XX = red[0][0]+red[0][1]+red[0][2]+red[0][3];
    float AA = red[1][0]+red[1][1]+red[1][2]+red[1][3];
    float SC = red[2][0]+red[2][1]+red[2][2]+red[2][3];
    float inv2s2 = 1.0f / (2.0f * sigma * sigma);
    prm[i*2+0] = inv2s2;
    prm[i*2+1] = AA;
    numer[i] = expf(-XX * inv2s2);
    float sp = log1pf(expf(0.3f - SC));
    atomicAdd(wsum + 1, sp * (1.0f / 1600.0f));
    int pos = atomicAdd(cnt + bp, 1);
    lst[bp * 1600 + pos] = i;
  }
}

// ---------------- top-5 helpers ----------------
__device__ __forceinline__ void sort5(float* c) {
  #define CE(i,j) { float hi = fmaxf(c[i], c[j]), lo = fminf(c[i], c[j]); c[i]=hi; c[j]=lo; }
  CE(0,1) CE(3,4) CE(2,4) CE(2,3) CE(1,4) CE(0,3) CE(0,2) CE(1,3) CE(1,2)
  #undef CE
}
__device__ __forceinline__ void ins5(float* t, float v) {
  float hi, lo;
  hi = fmaxf(t[0], v); lo = fminf(t[0], v); t[0] = hi; v = lo;
  hi = fmaxf(t[1], v); lo = fminf(t[1], v); t[1] = hi; v = lo;
  hi = fmaxf(t[2], v); lo = fminf(t[2], v); t[2] = hi; v = lo;
  hi = fmaxf(t[3], v); lo = fminf(t[3], v); t[3] = hi; v = lo;
  t[4] = fmaxf(t[4], v);
}

// ---------------- K3: fused dist + per-split top-5 (pipelined k-loop) ----------------
__global__ __launch_bounds__(256) void k_cross(const ushort* __restrict__ Pb,
    const ushort* __restrict__ Ab, const float* __restrict__ prm,
    const int* __restrict__ cnt, const int* __restrict__ lst,
    float* __restrict__ part) {
  int t = blockIdx.z;
  int n_t = min(cnt[t], 1600);
  int i0 = blockIdx.y * 32;
  if (i0 >= n_t) return;
  int j0 = blockIdx.x * 128;
  __shared__ int s_gis[32];
  __shared__ float s_red[4][32][6];
  int tid = threadIdx.x;
  if (tid < 32) {
    int gi = lst[t*1600 + min(i0 + tid, n_t - 1)];
    s_gis[tid] = min(max(gi, 0), NROW - 1);
  }
  __syncthreads();
  const int w = tid >> 6, lane = tid & 63, q = lane >> 4, m = lane & 15;
  const ushort* jp0 = Pb + ((size_t)(j0 + w*32 + m)*16 + t) * 256 + q*8;
  const ushort* jp1 = jp0 + (size_t)16*16*256;
  int gi0 = s_gis[m], gi1 = s_gis[16 + m];
  const ushort* ip0 = Ab + (size_t)gi0 * 256 + q*8;
  const ushort* ip1 = Ab + (size_t)gi1 * 256 + q*8;
  f32x4 acc[2][2];   // [jt][it]
  #pragma unroll
  for (int jt = 0; jt < 2; jt++)
    #pragma unroll
    for (int it = 0; it < 2; it++) { f32x4 z = {0.f,0.f,0.f,0.f}; acc[jt][it] = z; }
  // pipelined: prefetch k+1 while MFMA-ing k
  bf16x8 jc0 = *(const bf16x8*)(jp0);
  bf16x8 jc1 = *(const bf16x8*)(jp1);
  bf16x8 ic0 = *(const bf16x8*)(ip0);
  bf16x8 ic1 = *(const bf16x8*)(ip1);
  #pragma unroll
  for (int k = 0; k < 8; k++) {
    bf16x8 jn0, jn1, in0, in1;
    if (k < 7) {
      int o = (k + 1) * 32;
      jn0 = *(const bf16x8*)(jp0 + o);
      jn1 = *(const bf16x8*)(jp1 + o);
      in0 = *(const bf16x8*)(ip0 + o);
      in1 = *(const bf16x8*)(ip1 + o);
    }
    acc[0][0] = __builtin_amdgcn_mfma_f32_16x16x32_bf16(jc0, ic0, acc[0][0], 0, 0, 0);
    acc[0][1] = __builtin_amdgcn_mfma_f32_16x16x32_bf16(jc0, ic1, acc[0][1], 0, 0, 0);
    acc[1][0] = __builtin_amdgcn_mfma_f32_16x16x32_bf16(jc1, ic0, acc[1][0], 0, 0, 0);
    acc[1][1] = __builtin_amdgcn_mfma_f32_16x16x32_bf16(jc1, ic1, acc[1][1], 0, 0, 0);
    if (k < 7) { jc0 = jn0; jc1 = jn1; ic0 = in0; ic1 = in1; }
  }
  // per-lane top5/self per it-column. D: row(j) = 4q+reg (+jt*16), col(i) = m.
  float top[2][5], selfv[2] = {-1e30f, -1e30f};
  float p0i = prm[gi0*2], p0a = prm[gi0*2+1];
  float p1i = prm[gi1*2], p1a = prm[gi1*2+1];
  #pragma unroll
  for (int it = 0; it < 2; it++)
    #pragma unroll
    for (int k = 0; k < 5; k++) top[it][k] = -1e30f;
  #pragma unroll
  for (int jt = 0; jt < 2; jt++)
    #pragma unroll
    for (int reg = 0; reg < 4; reg++) {
      int j = j0 + w*32 + jt*16 + 4*q + reg;
      float d0 = -(1.0f - 2.0f*acc[jt][0][reg] + p0a) * p0i;
      float d1 = -(1.0f - 2.0f*acc[jt][1][reg] + p1a) * p1i;
      if (j == gi0) selfv[0] = d0; else ins5(top[0], d0);
      if (j == gi1) selfv[1] = d1; else ins5(top[1], d1);
    }
  // reduce over q (lane bits 4,5): bitonic 5-merge + self max
  #pragma unroll
  for (int mk = 16; mk <= 32; mk <<= 1) {
    #pragma unroll
    for (int it = 0; it < 2; it++) {
      float o[5], c[5];
      #pragma unroll
      for (int k = 0; k < 5; k++) o[k] = __shfl_xor(top[it][k], mk, 64);
      #pragma unroll
      for (int k = 0; k < 5; k++) c[k] = fmaxf(top[it][k], o[4 - k]);
      sort5(c);
      #pragma unroll
      for (int k = 0; k < 5; k++) top[it][k] = c[k];
      selfv[it] = fmaxf(selfv[it], __shfl_xor(selfv[it], mk, 64));
    }
  }
  if (q == 0) {
    #pragma unroll
    for (int it = 0; it < 2; it++) {
      #pragma unroll
      for (int k = 0; k < 5; k++) s_red[w][it*16 + m][k] = top[it][k];
      s_red[w][it*16 + m][5] = selfv[it];
    }
  }
  __syncthreads();
  if (tid < 32 && i0 + tid < n_t) {
    float T[5], S = s_red[0][tid][5];
    #pragma unroll
    for (int k = 0; k < 5; k++) T[k] = s_red[0][tid][k];
    #pragma unroll
    for (int w2 = 1; w2 < 4; w2++) {
      #pragma unroll
      for (int k = 0; k < 5; k++) ins5(T, s_red[w2][tid][k]);
      S = fmaxf(S, s_red[w2][tid][5]);
    }
    float* pp = part + ((size_t)s_gis[tid]*NSPLIT + blockIdx.x) * 6;
    #pragma unroll
    for (int k = 0; k < 5; k++) pp[k] = T[k];
    pp[5] = S;
  }
}

// ---------------- K4: parallel merge + last-block output write ----------------
__global__ __launch_bounds__(64) void k_merge(const float* __restrict__ part,
    const float* __restrict__ numer, float* __restrict__ wsum, int* __restrict__ done,
    const ushort* __restrict__ fe0, void* __restrict__ out) {
  int i = blockIdx.x * 64 + threadIdx.x;     // 25 blocks x 64 = 1600
  const float* pp = part + (size_t)i * NSPLIT * 6;
  float T[5]; float S = pp[5];
  #pragma unroll
  for (int k = 0; k < 5; k++) T[k] = pp[k];
  #pragma unroll
  for (int s = 1; s < NSPLIT; s++) {
    const float* ps = pp + s*6;
    float v0 = ps[0], v1 = ps[1], v2 = ps[2], v3 = ps[3], v4 = ps[4], v5 = ps[5];
    ins5(T, v0); ins5(T, v1); ins5(T, v2); ins5(T, v3); ins5(T, v4);
    S = fmaxf(S, v5);
  }
  float deno = expf(S);
  #pragma unroll
  for (int k = 0; k < 5; k++) deno += expf(T[k]);
  float local = numer[i] / deno;
  #pragma unroll
  for (int mk = 1; mk < 64; mk <<= 1) local += __shfl_xor(local, mk, 64);
  __shared__ int s_last;
  if (threadIdx.x == 0) {
    atomicAdd(wsum + 0, local * (1.0f / 1600.0f));
    __threadfence();                               // release our contribution
    s_last = (atomicAdd(done, 1) == 24);           // last of 25 blocks?
  }
  __syncthreads();
  if (s_last) {
    int f = sniff_f32(fe0, threadIdx.x);           // whole wave participates
    if (threadIdx.x == 0) {
      __threadfence();
      float brown = __hip_atomic_load(wsum + 0, __ATOMIC_RELAXED, __HIP_MEMORY_SCOPE_AGENT);
      float sp    = __hip_atomic_load(wsum + 1, __ATOMIC_RELAXED, __HIP_MEMORY_SCOPE_AGENT);
      if (f) {
        ((float*)out)[0] = brown;
        ((float*)out)[1] = sp;
      } else {
        ushort* o = (ushort*)out;
        o[0] = f2bf(brown);
        o[1] = f2bf(sp);
      }
    }
  }
}

extern "C" void kernel_launch(void* const* d_in, const int* in_sizes, int n_in,
                              void* d_out, int out_size, void* d_ws, size_t ws_size,
                              hipStream_t stream) {
  const ushort* fe0    = (const ushort*)d_in[0];
  const ushort* fe1    = (const ushort*)d_in[1];
  const ushort* W      = (const ushort*)d_in[2];
  const ushort* bias   = (const ushort*)d_in[3];
  const int*    bridge = (const int*)d_in[4];

  // workspace (~28.2 MB)
  ushort* Pb    = (ushort*)d_ws;               // 13,107,200
  ushort* Ab    = Pb + 13107200;               // 409,600
  ushort* Wt    = Ab + 409600;                 // 65,536
  float*  part  = (float*)(Wt + 65536);        // 1600*25*6 = 240,000
  float*  prm   = part + 240000;               // 3,200
  float*  numer = prm + 3200;                  // 1,600
  float*  wsum  = numer + 1600;                // 4 floats
  int*    cnt   = (int*)(wsum + 4);            // 16
  int*    done  = cnt + 16;                    // 1
  int*    lst   = done + 1;                    // 25,600

  k_prepw <<<256, 256, 0, stream>>>(W, Wt, (int*)wsum);   // also zeroes wsum/cnt/done
  k_proj  <<<800, 256, 0, stream>>>(fe0, fe1, Wt, bias, Pb);
  k_bridge<<<1600, 256, 0, stream>>>(Pb, bridge, Ab, prm, numer, cnt, lst, wsum);
  k_cross <<<dim3(NSPLIT, 13, 16), 256, 0, stream>>>(Pb, Ab, prm, cnt, lst, part);
  k_merge <<<25, 64, 0, stream>>>(part, numer, wsum, done, fe0, d_out);
}